// Round 16
// baseline (142.092 us; speedup 1.0000x reference)
//
#include <hip/hip_runtime.h>

// ---------- types ----------
typedef short short8 __attribute__((ext_vector_type(8)));        // 8 bf16 MFMA A/B frag
typedef float floatx4 __attribute__((ext_vector_type(4)));       // MFMA C/D frag

__device__ __forceinline__ unsigned short f2bf(float f) {
    unsigned u = __float_as_uint(f);
    u += 0x7fffu + ((u >> 16) & 1u);   // RNE
    return (unsigned short)(u >> 16);
}
__device__ __forceinline__ float bf2f(unsigned short b) {
    unsigned u = (unsigned)b << 16;
    return __uint_as_float(u);
}

#define MFMA16(a, b, c)  __builtin_amdgcn_mfma_f32_16x16x32_bf16((a), (b), (c), 0, 0, 0)

// ---------- ws layout (bytes) ----------
// q/k PACKED in MFMA-fragment order: element (row, d) at
//   ((rowtile*4 + ks)*64 + lane)*8 + e ; rowtile=row/16, lr=row%16, ks=d/32,
//   lk=(d%32)/8, e=d%8, lane=lk*16+lr.  One wave frag = one coalesced 1 KB txn.
static constexpr size_t Q_OFF    = 0;                    // q*QSCALE packed bf16 2 MB
static constexpr size_t K_OFF    = 2u << 20;             // k packed bf16        2 MB
static constexpr size_t U_OFF    = 4u << 20;             // u fp32 [8192]       32 KB
static constexpr size_t WFCT_OFF = U_OFF + 32768;        // W_fc packed bf16   256 KB
static constexpr size_t WGT_OFF  = WFCT_OFF + 262144;    // W_gate packed bf16
static constexpr size_t WQT_OFF  = WGT_OFF + 262144;     // W_q packed bf16     32 KB
static constexpr size_t WKT_OFF  = WQT_OFF + 32768;      // W_k packed bf16
static constexpr size_t WVO_OFF  = WKT_OFF + 32768;      // wvo fp32 [128] + c0
static constexpr size_t PB_OFF   = 5u << 20;             // partials float2 [8192][16] 1 MB

static constexpr int NSPLIT = 16;
// log2(e)/sqrt(128): folded into stored q so P = exp2(S)
static constexpr float QSCALE = 0.1275174308f;

// ---------- K1: weights -> MFMA-packed bf16 + wvo = W_v @ W_out GEMV ----------
__global__ void k_prep(const float* __restrict__ wfc, const float* __restrict__ wg,
                       const float* __restrict__ wq, const float* __restrict__ wk,
                       const float* __restrict__ wv, const float* __restrict__ wout,
                       const float* __restrict__ bv,
                       unsigned short* __restrict__ dfc, unsigned short* __restrict__ dg,
                       unsigned short* __restrict__ dq, unsigned short* __restrict__ dk,
                       float* __restrict__ wvo) {
    if (blockIdx.x == 1216) {
        // cooperative wvo GEMV in fp32: coalesced wv -> LDS, parallel per-row dots.
        __shared__ float wvls[128 * 132];
        __shared__ float wols[128];
        int t = threadIdx.x;
#pragma unroll
        for (int i = 0; i < 64; ++i) {
            int idx = t + i * 256;              // coalesced over wv[16384]
            int row = idx >> 7, col = idx & 127;
            wvls[row * 132 + col] = wv[idx];
        }
        if (t < 128) wols[t] = wout[t];
        __syncthreads();
        if (t < 128) {
            float s = 0.f;
            for (int j = 0; j < 128; ++j)
                s += wvls[t * 132 + j] * wols[j];
            wvo[t] = s;
        } else if (t == 128) {
            float s = 0.f;
            for (int j = 0; j < 128; ++j) s += bv[j] * wols[j];
            wvo[128] = s;   // c0
        }
        return;
    }
    int i = blockIdx.x * 256 + threadIdx.x;
    const float* s; unsigned short* d; int base, nchunk;
    if (i < 131072)      { s = wfc; d = dfc; nchunk = 32; base = 0; }
    else if (i < 262144) { s = wg;  d = dg;  nchunk = 32; base = 131072; }
    else if (i < 278528) { s = wq;  d = dq;  nchunk = 4;  base = 262144; }
    else if (i < 294912) { s = wk;  d = dk;  nchunk = 4;  base = 278528; }
    else return;
    int j = i - base;
    int kk = j >> 7, nn = j & 127;        // source W[kk][nn], row-major K x 128
    int t = nn >> 4, lr = nn & 15;
    int c = kk >> 5, lk = (kk >> 3) & 3, e = kk & 7;
    d[(((t * nchunk + c) * 64) + lr + 16 * lk) * 8 + e] = f2bf(s[j]);
}

// ---------- K2: fused gated-linear + QK + u (r12 structure + DEPTH-3 x prefetch) ----------
// grid 256 x 512 thr; block = 32 rows, 8 waves.
// Phase A: x fp32 staged->bf16 LDS (1 barrier/kc). Depth-3 register pipeline on the
//   x stream (named vars, rotated under #pragma unroll — NO arrays, r10 lesson) keeps
//   ~96 B/thread in flight so HBM latency is covered by 3 compute windows, not 1.
//   wave w: w<4 fc cols (w&3)*32, w>=4 gate. B-frags: coalesced 1KB packed-weight loads.
// Epilogue: gate->sigmoid LDS; fc -> h LDS; u = h @ wvo + c0; Phase B packed q/k out.
__global__ __launch_bounds__(512) void k_gq(const float* __restrict__ x,
                                            const unsigned short* __restrict__ wfcp,
                                            const unsigned short* __restrict__ wgp,
                                            const float* __restrict__ bfc,
                                            const float* __restrict__ bg,
                                            const unsigned short* __restrict__ wqp,
                                            const unsigned short* __restrict__ wkp,
                                            const float* __restrict__ bq,
                                            const float* __restrict__ bk,
                                            const float* __restrict__ wvo,
                                            unsigned short* __restrict__ qpk,
                                            unsigned short* __restrict__ kpk,
                                            float* __restrict__ ug) {
    __shared__ __align__(16) unsigned short xs[2][32 * 136];
    __shared__ __align__(16) float gbuf[32 * 132];
    __shared__ __align__(16) unsigned short hs[32 * 136];
    const int tid = threadIdx.x;
    const int i0 = blockIdx.x * 32;
    const int w = tid >> 6, lane = tid & 63;
    const int lr = lane & 15, lk = lane >> 4;

    const int isg = (w >= 4);
    const int wq4 = w & 3;                 // 0..3: which 32-col group
    const unsigned short* wp = isg ? wgp : wfcp;

    floatx4 acc[2][2];
#pragma unroll
    for (int mt = 0; mt < 2; ++mt)
#pragma unroll
        for (int nt = 0; nt < 2; ++nt) acc[mt][nt] = (floatx4)0.0f;

    const int srow = tid >> 4, se = tid & 15;   // 32 rows x 16 thr, 8 floats each
    const float* gp0 = x + (size_t)(i0 + srow) * 1024 + se * 8;
    // depth-3 x pipeline (named registers, rotated; loop unrolled -> copies are renames)
    float4 ra0 = *(const float4*)(gp0);
    float4 rb0 = *(const float4*)(gp0 + 4);
    float4 ra1 = *(const float4*)(gp0 + 128);
    float4 rb1 = *(const float4*)(gp0 + 132);
    float4 ra2 = *(const float4*)(gp0 + 256);
    float4 rb2 = *(const float4*)(gp0 + 260);

#pragma unroll
    for (int kc = 0; kc < 8; ++kc) {
        {   // commit oldest chunk to LDS buf kc&1 (fp32 -> bf16)
            short8 t;
            unsigned short* tp = (unsigned short*)&t;
            tp[0] = f2bf(ra0.x); tp[1] = f2bf(ra0.y); tp[2] = f2bf(ra0.z); tp[3] = f2bf(ra0.w);
            tp[4] = f2bf(rb0.x); tp[5] = f2bf(rb0.y); tp[6] = f2bf(rb0.z); tp[7] = f2bf(rb0.w);
            *(short8*)(xs[kc & 1] + srow * 136 + se * 8) = t;
        }
        // rotate pipeline; issue load for chunk kc+3
        ra0 = ra1; rb0 = rb1;
        ra1 = ra2; rb1 = rb2;
        if (kc < 5) {
            const float* gp = gp0 + (kc + 3) * 128;
            ra2 = *(const float4*)gp;
            rb2 = *(const float4*)(gp + 4);
        }
        __syncthreads();
        const unsigned short* xb = xs[kc & 1];
#pragma unroll
        for (int ks = 0; ks < 4; ++ks) {
            const int c = kc * 4 + ks;
            short8 a[2], b[2];
#pragma unroll
            for (int mt = 0; mt < 2; ++mt)
                a[mt] = *(const short8*)(xb + (mt * 16 + lr) * 136 + ks * 32 + lk * 8);
#pragma unroll
            for (int nt = 0; nt < 2; ++nt)
                b[nt] = *(const short8*)(wp + ((((size_t)(wq4 * 2 + nt)) * 32 + c) * 64 + lane) * 8);
#pragma unroll
            for (int mt = 0; mt < 2; ++mt)
#pragma unroll
                for (int nt = 0; nt < 2; ++nt)
                    acc[mt][nt] = MFMA16(a[mt], b[nt], acc[mt][nt]);
        }
    }
    __syncthreads();
    // epilogue A: gate waves write sigmoid; fc waves combine -> h
    if (isg) {
#pragma unroll
        for (int mt = 0; mt < 2; ++mt)
#pragma unroll
            for (int nt = 0; nt < 2; ++nt) {
                int col = wq4 * 32 + nt * 16 + lr;
                float bb = bg[col];
#pragma unroll
                for (int r = 0; r < 4; ++r) {
                    float v = acc[mt][nt][r] + bb;
                    gbuf[(mt * 16 + lk * 4 + r) * 132 + col] =
                        __builtin_amdgcn_rcpf(1.0f + __builtin_amdgcn_exp2f(-1.4426950408889634f * v));
                }
            }
    }
    __syncthreads();
    if (!isg) {
#pragma unroll
        for (int mt = 0; mt < 2; ++mt)
#pragma unroll
            for (int nt = 0; nt < 2; ++nt) {
                int col = wq4 * 32 + nt * 16 + lr;
                float bb = bfc[col];
#pragma unroll
                for (int r = 0; r < 4; ++r) {
                    int row = mt * 16 + lk * 4 + r;
                    hs[row * 136 + col] = f2bf((acc[mt][nt][r] + bb) * gbuf[row * 132 + col]);
                }
            }
    }
    __syncthreads();

    // u[i] = h[i] @ wvo + c0 : thread t -> row t>>4, 8-elem chunk (t&15)*8
    {
        int row = tid >> 4, c = tid & 15;
        float s = 0.f;
#pragma unroll
        for (int e = 0; e < 8; ++e)
            s += bf2f(hs[row * 136 + c * 8 + e]) * wvo[c * 8 + e];
#pragma unroll
        for (int d = 1; d < 16; d <<= 1) s += __shfl_xor(s, d);
        if (c == 0) ug[i0 + row] = s + wvo[128];
    }

    // Phase B: q (w<4) | k (w>=4), 32 cols per wave, packed B
    floatx4 qacc[2][2];
#pragma unroll
    for (int mt = 0; mt < 2; ++mt)
#pragma unroll
        for (int nt = 0; nt < 2; ++nt) qacc[mt][nt] = (floatx4)0.0f;
    const unsigned short* wbp = (w < 4) ? wqp : wkp;
#pragma unroll
    for (int ks = 0; ks < 4; ++ks) {
        short8 a[2], b[2];
#pragma unroll
        for (int mt = 0; mt < 2; ++mt)
            a[mt] = *(const short8*)(hs + (mt * 16 + lr) * 136 + ks * 32 + lk * 8);
#pragma unroll
        for (int nt = 0; nt < 2; ++nt)
            b[nt] = *(const short8*)(wbp + ((((size_t)(wq4 * 2 + nt)) * 4 + ks) * 64 + lane) * 8);
#pragma unroll
        for (int mt = 0; mt < 2; ++mt)
#pragma unroll
            for (int nt = 0; nt < 2; ++nt)
                qacc[mt][nt] = MFMA16(a[mt], b[nt], qacc[mt][nt]);
    }
    // epilogue B: bias+scale -> LDS tile (xs reused: [0]=q, [1]=k)
    {
        unsigned short* dstl = xs[isg];
        const float* bb_ = (w < 4) ? bq : bk;
        const float sc = (w < 4) ? QSCALE : 1.0f;
#pragma unroll
        for (int mt = 0; mt < 2; ++mt)
#pragma unroll
            for (int nt = 0; nt < 2; ++nt) {
                int col = wq4 * 32 + nt * 16 + lr;
                float bb = bb_[col];
#pragma unroll
                for (int r = 0; r < 4; ++r)
                    dstl[(mt * 16 + lk * 4 + r) * 136 + col] = f2bf((qacc[mt][nt][r] + bb) * sc);
            }
    }
    __syncthreads();
    // cooperative packed store: 16 segments (sel,rtl,ks), wave w -> sel=w>>2, 2 ks each
    {
        int sel = w >> 2, p = w & 3;
        int rtl = p >> 1, ks2 = (p & 1) * 2;
        unsigned short* gdst = sel ? kpk : qpk;
        const unsigned short* src = xs[sel];
        size_t rt = (i0 >> 4) + rtl;
#pragma unroll
        for (int s = 0; s < 2; ++s) {
            int ks = ks2 + s;
            short8 v = *(const short8*)(src + (rtl * 16 + lr) * 136 + ks * 32 + lk * 8);
            *(short8*)(gdst + ((rt * 4 + ks) * 64 + lane) * 8) = v;
        }
    }
}

// ---------- K3: flash v8 — LDS-free, barrier-free, single wave-round (r12 verbatim) ----------
// grid (32, 16) x 256 thr; block = 256 q-rows, wave w owns rows w*64..+64 (4 row-tiles).
// 32 j sub-tiles per split; per sub-tile: 4 coalesced K-frag loads (prefetched 1 ahead)
// + u float4; 16 MFMA + exp2/fma. Partials transposed: float2(n,l)[row][16].
// launch_bounds(256,1): ~160 VGPR — do NOT cap below (r6: cap 128 -> spill storm).
// Keep this kernel's epilogue MINIMAL (r14: fused atomic epilogue broke qf residency).
__global__ __launch_bounds__(256, 1) void k_flash(const unsigned short* __restrict__ qp,
                                                  const unsigned short* __restrict__ kp,
                                                  const float* __restrict__ ug,
                                                  float2* __restrict__ pb) {
    const int tid = threadIdx.x;
    const int w = tid >> 6, lane = tid & 63;
    const int lr = lane & 15, lk = lane >> 4;
    const int rt0 = blockIdx.x * 16 + w * 4;    // q row-tile base

    // Q frags: 16 coalesced 1KB loads, live in registers
    short8 qf[4][4];
#pragma unroll
    for (int mt = 0; mt < 4; ++mt)
#pragma unroll
        for (int ks = 0; ks < 4; ++ks)
            qf[mt][ks] = *(const short8*)(qp + (((size_t)(rt0 + mt) * 4 + ks) * 64 + lane) * 8);

    float numv[4] = {0.f, 0.f, 0.f, 0.f};
    float lsum[4] = {0.f, 0.f, 0.f, 0.f};

    const int jt0 = blockIdx.y * 32;            // 32 j row-tiles per split

    short8 af[4], afn[4];
    floatx4 uu, uun;
#pragma unroll
    for (int ks = 0; ks < 4; ++ks)
        af[ks] = *(const short8*)(kp + (((size_t)jt0 * 4 + ks) * 64 + lane) * 8);
    uu = *(const floatx4*)(ug + jt0 * 16 + lk * 4);

    for (int t = 0; t < 32; ++t) {
        if (t < 31) {   // prefetch next sub-tile (stays in flight across the MFMAs)
#pragma unroll
            for (int ks = 0; ks < 4; ++ks)
                afn[ks] = *(const short8*)(kp + (((size_t)(jt0 + t + 1) * 4 + ks) * 64 + lane) * 8);
            uun = *(const floatx4*)(ug + (jt0 + t + 1) * 16 + lk * 4);
        }
        floatx4 sacc[4];
#pragma unroll
        for (int mt = 0; mt < 4; ++mt) sacc[mt] = (floatx4)0.0f;
#pragma unroll
        for (int ks = 0; ks < 4; ++ks)
#pragma unroll
            for (int mt = 0; mt < 4; ++mt)
                sacc[mt] = MFMA16(af[ks], qf[mt][ks], sacc[mt]);
#pragma unroll
        for (int mt = 0; mt < 4; ++mt) {
#pragma unroll
            for (int r = 0; r < 4; ++r) {
                float p = __builtin_amdgcn_exp2f(sacc[mt][r]);
                numv[mt] += p * uu[r];
                lsum[mt] += p;
            }
        }
#pragma unroll
        for (int ks = 0; ks < 4; ++ks) af[ks] = afn[ks];
        uu = uun;
    }

    // reduce over lk (lane bits 4,5); store transposed packed partial (n,l)
#pragma unroll
    for (int mt = 0; mt < 4; ++mt) {
        float n = numv[mt], l = lsum[mt];
        n += __shfl_xor(n, 16); n += __shfl_xor(n, 32);
        l += __shfl_xor(l, 16); l += __shfl_xor(l, 32);
        if (lk == 0) {
            size_t row = (size_t)(rt0 + mt) * 16 + lr;
            pb[row * NSPLIT + blockIdx.y] = make_float2(n, l);
        }
    }
}

// ---------- K4: out[row] = (sum_s n_s) / (sum_s l_s) + b_out ----------
// one thread per row; 128 B coalesced read of the row's 16 float2 partials.
__global__ __launch_bounds__(256) void k_out(const float2* __restrict__ pb,
                                             const float* __restrict__ bout,
                                             float* __restrict__ out) {
    int row = blockIdx.x * 256 + threadIdx.x;
    const float2* p = pb + (size_t)row * NSPLIT;
    float n = 0.f, l = 0.f;
#pragma unroll
    for (int s = 0; s < NSPLIT; ++s) {
        float2 v = p[s];
        n += v.x; l += v.y;
    }
    out[row] = n / l + bout[0];
}

// ---------- launch ----------
extern "C" void kernel_launch(void* const* d_in, const int* in_sizes, int n_in,
                              void* d_out, int out_size, void* d_ws, size_t ws_size,
                              hipStream_t stream) {
    const float* x    = (const float*)d_in[0];
    const float* Wfc  = (const float*)d_in[1];
    const float* bfc  = (const float*)d_in[2];
    const float* Wg   = (const float*)d_in[3];
    const float* bg   = (const float*)d_in[4];
    const float* Wq   = (const float*)d_in[5];
    const float* bq   = (const float*)d_in[6];
    const float* Wk   = (const float*)d_in[7];
    const float* bk   = (const float*)d_in[8];
    const float* Wv   = (const float*)d_in[9];
    const float* bv   = (const float*)d_in[10];
    const float* Wout = (const float*)d_in[11];
    const float* bout = (const float*)d_in[12];
    char* ws = (char*)d_ws;

    unsigned short* qb   = (unsigned short*)(ws + Q_OFF);
    unsigned short* kb   = (unsigned short*)(ws + K_OFF);
    float*          ub   = (float*)(ws + U_OFF);
    unsigned short* wfcp = (unsigned short*)(ws + WFCT_OFF);
    unsigned short* wgp  = (unsigned short*)(ws + WGT_OFF);
    unsigned short* wqp  = (unsigned short*)(ws + WQT_OFF);
    unsigned short* wkp  = (unsigned short*)(ws + WKT_OFF);
    float*          wvo  = (float*)(ws + WVO_OFF);
    float2*         pbb  = (float2*)(ws + PB_OFF);

    k_prep<<<1217, 256, 0, stream>>>(Wfc, Wg, Wq, Wk, Wv, Wout, bv, wfcp, wgp, wqp, wkp, wvo);
    k_gq<<<256, 512, 0, stream>>>(x, wfcp, wgp, bfc, bg, wqp, wkp, bq, bk, wvo, qb, kb, ub);

    dim3 gf(32, NSPLIT);
    k_flash<<<gf, 256, 0, stream>>>(qb, kb, ub, pbb);

    k_out<<<32, 256, 0, stream>>>(pbb, bout, (float*)d_out);
}

// Round 17
// 133.668 us; speedup vs baseline: 1.0630x; 1.0630x over previous
//
#include <hip/hip_runtime.h>

// ---------- types ----------
typedef short short8 __attribute__((ext_vector_type(8)));        // 8 bf16 MFMA A/B frag
typedef float floatx4 __attribute__((ext_vector_type(4)));       // MFMA C/D frag

__device__ __forceinline__ unsigned short f2bf(float f) {
    unsigned u = __float_as_uint(f);
    u += 0x7fffu + ((u >> 16) & 1u);   // RNE
    return (unsigned short)(u >> 16);
}
__device__ __forceinline__ float bf2f(unsigned short b) {
    unsigned u = (unsigned)b << 16;
    return __uint_as_float(u);
}

#define MFMA16(a, b, c)  __builtin_amdgcn_mfma_f32_16x16x32_bf16((a), (b), (c), 0, 0, 0)

// ---------- ws layout (bytes) ----------
// q/k PACKED in MFMA-fragment order: element (row, d) at
//   ((rowtile*4 + ks)*64 + lane)*8 + e ; rowtile=row/16, lr=row%16, ks=d/32,
//   lk=(d%32)/8, e=d%8, lane=lk*16+lr.  One wave frag = one coalesced 1 KB txn.
static constexpr size_t Q_OFF    = 0;                    // q*QSCALE packed bf16 2 MB
static constexpr size_t K_OFF    = 2u << 20;             // k packed bf16        2 MB
static constexpr size_t U_OFF    = 4u << 20;             // u fp32 [8192]       32 KB
static constexpr size_t WFCT_OFF = U_OFF + 32768;        // W_fc packed bf16   256 KB
static constexpr size_t WGT_OFF  = WFCT_OFF + 262144;    // W_gate packed bf16
static constexpr size_t WQT_OFF  = WGT_OFF + 262144;     // W_q packed bf16     32 KB
static constexpr size_t WKT_OFF  = WQT_OFF + 32768;      // W_k packed bf16
static constexpr size_t WVO_OFF  = WKT_OFF + 32768;      // wvo fp32 [128] + c0
static constexpr size_t PB_OFF   = 5u << 20;             // partials float2 [8192][16] 1 MB

static constexpr int NSPLIT = 16;
// log2(e)/sqrt(128): folded into stored q so P = exp2(S)
static constexpr float QSCALE = 0.1275174308f;

// ---------- K1: weights -> MFMA-packed bf16 + wvo = W_v @ W_out GEMV ----------
__global__ void k_prep(const float* __restrict__ wfc, const float* __restrict__ wg,
                       const float* __restrict__ wq, const float* __restrict__ wk,
                       const float* __restrict__ wv, const float* __restrict__ wout,
                       const float* __restrict__ bv,
                       unsigned short* __restrict__ dfc, unsigned short* __restrict__ dg,
                       unsigned short* __restrict__ dq, unsigned short* __restrict__ dk,
                       float* __restrict__ wvo) {
    if (blockIdx.x == 1216) {
        int t = threadIdx.x;
        if (t < 128) {
            float s = 0.f;
            for (int j = 0; j < 128; ++j) s += wv[t * 128 + j] * wout[j];
            wvo[t] = s;
        } else if (t == 128) {
            float s = 0.f;
            for (int j = 0; j < 128; ++j) s += bv[j] * wout[j];
            wvo[128] = s;   // c0
        }
        return;
    }
    int i = blockIdx.x * 256 + threadIdx.x;
    const float* s; unsigned short* d; int base, nchunk;
    if (i < 131072)      { s = wfc; d = dfc; nchunk = 32; base = 0; }
    else if (i < 262144) { s = wg;  d = dg;  nchunk = 32; base = 131072; }
    else if (i < 278528) { s = wq;  d = dq;  nchunk = 4;  base = 262144; }
    else if (i < 294912) { s = wk;  d = dk;  nchunk = 4;  base = 278528; }
    else return;
    int j = i - base;
    int kk = j >> 7, nn = j & 127;        // source W[kk][nn], row-major K x 128
    int t = nn >> 4, lr = nn & 15;
    int c = kk >> 5, lk = (kk >> 3) & 3, e = kk & 7;
    d[(((t * nchunk + c) * 64) + lr + 16 * lk) * 8 + e] = f2bf(s[j]);
}

// ---------- K2: fused gated-linear + QK + u (r12 structure: LDS-staged Phase A) ----------
// grid 256 x 512 thr; block = 32 rows, 8 waves.
// Phase A: x fp32 staged->bf16 LDS (reg-prefetch dbuf, 1 barrier/kc) — staging dedups
//   both global traffic and the f2bf conversion across the 8 waves.
//   wave w: w<4 fc cols (w&3)*32, w>=4 gate. B-frags: coalesced 1KB packed-weight loads.
// Epilogue: gate->sigmoid LDS; fc -> h LDS; u = h @ wvo + c0; Phase B packed q/k out.
__global__ __launch_bounds__(512) void k_gq(const float* __restrict__ x,
                                            const unsigned short* __restrict__ wfcp,
                                            const unsigned short* __restrict__ wgp,
                                            const float* __restrict__ bfc,
                                            const float* __restrict__ bg,
                                            const unsigned short* __restrict__ wqp,
                                            const unsigned short* __restrict__ wkp,
                                            const float* __restrict__ bq,
                                            const float* __restrict__ bk,
                                            const float* __restrict__ wvo,
                                            unsigned short* __restrict__ qpk,
                                            unsigned short* __restrict__ kpk,
                                            float* __restrict__ ug) {
    __shared__ __align__(16) unsigned short xs[2][32 * 136];
    __shared__ __align__(16) float gbuf[32 * 132];
    __shared__ __align__(16) unsigned short hs[32 * 136];
    const int tid = threadIdx.x;
    const int i0 = blockIdx.x * 32;
    const int w = tid >> 6, lane = tid & 63;
    const int lr = lane & 15, lk = lane >> 4;

    const int isg = (w >= 4);
    const int wq4 = w & 3;                 // 0..3: which 32-col group
    const unsigned short* wp = isg ? wgp : wfcp;

    floatx4 acc[2][2];
#pragma unroll
    for (int mt = 0; mt < 2; ++mt)
#pragma unroll
        for (int nt = 0; nt < 2; ++nt) acc[mt][nt] = (floatx4)0.0f;

    const int srow = tid >> 4, se = tid & 15;   // 32 rows x 16 thr, 8 floats each
    const float* gp0 = x + (size_t)(i0 + srow) * 1024 + se * 8;
    float4 ra = *(const float4*)gp0;
    float4 rb = *(const float4*)(gp0 + 4);

    for (int kc = 0; kc < 8; ++kc) {
        {   // commit prefetched chunk to LDS buf kc&1 (fp32 -> bf16)
            short8 t;
            unsigned short* tp = (unsigned short*)&t;
            tp[0] = f2bf(ra.x); tp[1] = f2bf(ra.y); tp[2] = f2bf(ra.z); tp[3] = f2bf(ra.w);
            tp[4] = f2bf(rb.x); tp[5] = f2bf(rb.y); tp[6] = f2bf(rb.z); tp[7] = f2bf(rb.w);
            *(short8*)(xs[kc & 1] + srow * 136 + se * 8) = t;
        }
        if (kc < 7) {
            const float* gp = gp0 + (kc + 1) * 128;
            ra = *(const float4*)gp;
            rb = *(const float4*)(gp + 4);
        }
        __syncthreads();
        const unsigned short* xb = xs[kc & 1];
#pragma unroll
        for (int ks = 0; ks < 4; ++ks) {
            const int c = kc * 4 + ks;
            short8 a[2], b[2];
#pragma unroll
            for (int mt = 0; mt < 2; ++mt)
                a[mt] = *(const short8*)(xb + (mt * 16 + lr) * 136 + ks * 32 + lk * 8);
#pragma unroll
            for (int nt = 0; nt < 2; ++nt)
                b[nt] = *(const short8*)(wp + ((((size_t)(wq4 * 2 + nt)) * 32 + c) * 64 + lane) * 8);
#pragma unroll
            for (int mt = 0; mt < 2; ++mt)
#pragma unroll
                for (int nt = 0; nt < 2; ++nt)
                    acc[mt][nt] = MFMA16(a[mt], b[nt], acc[mt][nt]);
        }
    }
    __syncthreads();
    // epilogue A: gate waves write sigmoid; fc waves combine -> h
    if (isg) {
#pragma unroll
        for (int mt = 0; mt < 2; ++mt)
#pragma unroll
            for (int nt = 0; nt < 2; ++nt) {
                int col = wq4 * 32 + nt * 16 + lr;
                float bb = bg[col];
#pragma unroll
                for (int r = 0; r < 4; ++r) {
                    float v = acc[mt][nt][r] + bb;
                    gbuf[(mt * 16 + lk * 4 + r) * 132 + col] =
                        __builtin_amdgcn_rcpf(1.0f + __builtin_amdgcn_exp2f(-1.4426950408889634f * v));
                }
            }
    }
    __syncthreads();
    if (!isg) {
#pragma unroll
        for (int mt = 0; mt < 2; ++mt)
#pragma unroll
            for (int nt = 0; nt < 2; ++nt) {
                int col = wq4 * 32 + nt * 16 + lr;
                float bb = bfc[col];
#pragma unroll
                for (int r = 0; r < 4; ++r) {
                    int row = mt * 16 + lk * 4 + r;
                    hs[row * 136 + col] = f2bf((acc[mt][nt][r] + bb) * gbuf[row * 132 + col]);
                }
            }
    }
    __syncthreads();

    // u[i] = h[i] @ wvo + c0 : thread t -> row t>>4, 8-elem chunk (t&15)*8
    {
        int row = tid >> 4, c = tid & 15;
        float s = 0.f;
#pragma unroll
        for (int e = 0; e < 8; ++e)
            s += bf2f(hs[row * 136 + c * 8 + e]) * wvo[c * 8 + e];
#pragma unroll
        for (int d = 1; d < 16; d <<= 1) s += __shfl_xor(s, d);
        if (c == 0) ug[i0 + row] = s + wvo[128];
    }

    // Phase B: q (w<4) | k (w>=4), 32 cols per wave, packed B
    floatx4 qacc[2][2];
#pragma unroll
    for (int mt = 0; mt < 2; ++mt)
#pragma unroll
        for (int nt = 0; nt < 2; ++nt) qacc[mt][nt] = (floatx4)0.0f;
    const unsigned short* wbp = (w < 4) ? wqp : wkp;
#pragma unroll
    for (int ks = 0; ks < 4; ++ks) {
        short8 a[2], b[2];
#pragma unroll
        for (int mt = 0; mt < 2; ++mt)
            a[mt] = *(const short8*)(hs + (mt * 16 + lr) * 136 + ks * 32 + lk * 8);
#pragma unroll
        for (int nt = 0; nt < 2; ++nt)
            b[nt] = *(const short8*)(wbp + ((((size_t)(wq4 * 2 + nt)) * 4 + ks) * 64 + lane) * 8);
#pragma unroll
        for (int mt = 0; mt < 2; ++mt)
#pragma unroll
            for (int nt = 0; nt < 2; ++nt)
                qacc[mt][nt] = MFMA16(a[mt], b[nt], qacc[mt][nt]);
    }
    // epilogue B: bias+scale -> LDS tile (xs reused: [0]=q, [1]=k)
    {
        unsigned short* dstl = xs[isg];
        const float* bb_ = (w < 4) ? bq : bk;
        const float sc = (w < 4) ? QSCALE : 1.0f;
#pragma unroll
        for (int mt = 0; mt < 2; ++mt)
#pragma unroll
            for (int nt = 0; nt < 2; ++nt) {
                int col = wq4 * 32 + nt * 16 + lr;
                float bb = bb_[col];
#pragma unroll
                for (int r = 0; r < 4; ++r)
                    dstl[(mt * 16 + lk * 4 + r) * 136 + col] = f2bf((qacc[mt][nt][r] + bb) * sc);
            }
    }
    __syncthreads();
    // cooperative packed store: 16 segments (sel,rtl,ks), wave w -> sel=w>>2, 2 ks each
    {
        int sel = w >> 2, p = w & 3;
        int rtl = p >> 1, ks2 = (p & 1) * 2;
        unsigned short* gdst = sel ? kpk : qpk;
        const unsigned short* src = xs[sel];
        size_t rt = (i0 >> 4) + rtl;
#pragma unroll
        for (int s = 0; s < 2; ++s) {
            int ks = ks2 + s;
            short8 v = *(const short8*)(src + (rtl * 16 + lr) * 136 + ks * 32 + lk * 8);
            *(short8*)(gdst + ((rt * 4 + ks) * 64 + lane) * 8) = v;
        }
    }
}

// ---------- K3: flash v8 — LDS-free, barrier-free, single wave-round (r12 verbatim) ----------
// grid (32, 16) x 256 thr; block = 256 q-rows, wave w owns rows w*64..+64 (4 row-tiles).
// 32 j sub-tiles per split; per sub-tile: 4 coalesced K-frag loads (prefetched 1 ahead)
// + u float4; 16 MFMA + exp2/fma. Partials transposed: float2(n,l)[row][16].
// launch_bounds(256,1): ~160 VGPR — do NOT cap below (r6: cap 128 -> spill storm).
// Keep this kernel's epilogue MINIMAL (r14: fused atomic epilogue broke qf residency).
__global__ __launch_bounds__(256, 1) void k_flash(const unsigned short* __restrict__ qp,
                                                  const unsigned short* __restrict__ kp,
                                                  const float* __restrict__ ug,
                                                  float2* __restrict__ pb) {
    const int tid = threadIdx.x;
    const int w = tid >> 6, lane = tid & 63;
    const int lr = lane & 15, lk = lane >> 4;
    const int rt0 = blockIdx.x * 16 + w * 4;    // q row-tile base

    // Q frags: 16 coalesced 1KB loads, live in registers
    short8 qf[4][4];
#pragma unroll
    for (int mt = 0; mt < 4; ++mt)
#pragma unroll
        for (int ks = 0; ks < 4; ++ks)
            qf[mt][ks] = *(const short8*)(qp + (((size_t)(rt0 + mt) * 4 + ks) * 64 + lane) * 8);

    float numv[4] = {0.f, 0.f, 0.f, 0.f};
    float lsum[4] = {0.f, 0.f, 0.f, 0.f};

    const int jt0 = blockIdx.y * 32;            // 32 j row-tiles per split

    short8 af[4], afn[4];
    floatx4 uu, uun;
#pragma unroll
    for (int ks = 0; ks < 4; ++ks)
        af[ks] = *(const short8*)(kp + (((size_t)jt0 * 4 + ks) * 64 + lane) * 8);
    uu = *(const floatx4*)(ug + jt0 * 16 + lk * 4);

    for (int t = 0; t < 32; ++t) {
        if (t < 31) {   // prefetch next sub-tile (stays in flight across the MFMAs)
#pragma unroll
            for (int ks = 0; ks < 4; ++ks)
                afn[ks] = *(const short8*)(kp + (((size_t)(jt0 + t + 1) * 4 + ks) * 64 + lane) * 8);
            uun = *(const floatx4*)(ug + (jt0 + t + 1) * 16 + lk * 4);
        }
        floatx4 sacc[4];
#pragma unroll
        for (int mt = 0; mt < 4; ++mt) sacc[mt] = (floatx4)0.0f;
#pragma unroll
        for (int ks = 0; ks < 4; ++ks)
#pragma unroll
            for (int mt = 0; mt < 4; ++mt)
                sacc[mt] = MFMA16(af[ks], qf[mt][ks], sacc[mt]);
#pragma unroll
        for (int mt = 0; mt < 4; ++mt) {
#pragma unroll
            for (int r = 0; r < 4; ++r) {
                float p = __builtin_amdgcn_exp2f(sacc[mt][r]);
                numv[mt] += p * uu[r];
                lsum[mt] += p;
            }
        }
#pragma unroll
        for (int ks = 0; ks < 4; ++ks) af[ks] = afn[ks];
        uu = uun;
    }

    // reduce over lk (lane bits 4,5); store transposed packed partial (n,l)
#pragma unroll
    for (int mt = 0; mt < 4; ++mt) {
        float n = numv[mt], l = lsum[mt];
        n += __shfl_xor(n, 16); n += __shfl_xor(n, 32);
        l += __shfl_xor(l, 16); l += __shfl_xor(l, 32);
        if (lk == 0) {
            size_t row = (size_t)(rt0 + mt) * 16 + lr;
            pb[row * NSPLIT + blockIdx.y] = make_float2(n, l);
        }
    }
}

// ---------- K4: out[row] = (sum_s n_s) / (sum_s l_s) + b_out ----------
// one thread per row; 128 B coalesced read of the row's 16 float2 partials.
__global__ __launch_bounds__(256) void k_out(const float2* __restrict__ pb,
                                             const float* __restrict__ bout,
                                             float* __restrict__ out) {
    int row = blockIdx.x * 256 + threadIdx.x;
    const float2* p = pb + (size_t)row * NSPLIT;
    float n = 0.f, l = 0.f;
#pragma unroll
    for (int s = 0; s < NSPLIT; ++s) {
        float2 v = p[s];
        n += v.x; l += v.y;
    }
    out[row] = n / l + bout[0];
}

// ---------- launch ----------
extern "C" void kernel_launch(void* const* d_in, const int* in_sizes, int n_in,
                              void* d_out, int out_size, void* d_ws, size_t ws_size,
                              hipStream_t stream) {
    const float* x    = (const float*)d_in[0];
    const float* Wfc  = (const float*)d_in[1];
    const float* bfc  = (const float*)d_in[2];
    const float* Wg   = (const float*)d_in[3];
    const float* bg   = (const float*)d_in[4];
    const float* Wq   = (const float*)d_in[5];
    const float* bq   = (const float*)d_in[6];
    const float* Wk   = (const float*)d_in[7];
    const float* bk   = (const float*)d_in[8];
    const float* Wv   = (const float*)d_in[9];
    const float* bv   = (const float*)d_in[10];
    const float* Wout = (const float*)d_in[11];
    const float* bout = (const float*)d_in[12];
    char* ws = (char*)d_ws;

    unsigned short* qb   = (unsigned short*)(ws + Q_OFF);
    unsigned short* kb   = (unsigned short*)(ws + K_OFF);
    float*          ub   = (float*)(ws + U_OFF);
    unsigned short* wfcp = (unsigned short*)(ws + WFCT_OFF);
    unsigned short* wgp  = (unsigned short*)(ws + WGT_OFF);
    unsigned short* wqp  = (unsigned short*)(ws + WQT_OFF);
    unsigned short* wkp  = (unsigned short*)(ws + WKT_OFF);
    float*          wvo  = (float*)(ws + WVO_OFF);
    float2*         pbb  = (float2*)(ws + PB_OFF);

    k_prep<<<1217, 256, 0, stream>>>(Wfc, Wg, Wq, Wk, Wv, Wout, bv, wfcp, wgp, wqp, wkp, wvo);
    k_gq<<<256, 512, 0, stream>>>(x, wfcp, wgp, bfc, bg, wqp, wkp, bq, bk, wvo, qb, kb, ub);

    dim3 gf(32, NSPLIT);
    k_flash<<<gf, 256, 0, stream>>>(qb, kb, ub, pbb);

    k_out<<<32, 256, 0, stream>>>(pbb, bout, (float*)d_out);
}